// Round 8
// baseline (1224.564 us; speedup 1.0000x reference)
//
#include <hip/hip_runtime.h>
#include <hip/hip_bf16.h>
#include <stdint.h>

#define T_TOK  8192
#define DIM_   1024
#define HID_   2816
#define NEXP   8

typedef __bf16 bf16x8 __attribute__((ext_vector_type(8)));
typedef float  f32x4  __attribute__((ext_vector_type(4)));

__device__ __forceinline__ unsigned short f2bf(float f) {
  uint32_t u = __float_as_uint(f);
  u += 0x7FFFu + ((u >> 16) & 1u);
  return (unsigned short)(u >> 16);
}

__device__ __forceinline__ void gld_lds16(const void* g, void* l) {
  __builtin_amdgcn_global_load_lds(
      (const __attribute__((address_space(1))) uint32_t*)g,
      (__attribute__((address_space(3))) uint32_t*)l, 16, 0, 0);
}

// Swizzled LDS index for a [*][64]-ushort tile: 16B unit (col>>3) XOR (row&7).
__device__ __forceinline__ int lds_idx(int row, int col) {
  return row * 64 + ((((col >> 3) ^ (row & 7)) & 7) << 3);
}

// ---------------- cast x fp32 -> bf16 ----------------
__global__ __launch_bounds__(256) void cast_x_kernel(const float* __restrict__ in,
                                                     unsigned short* __restrict__ out) {
  int i = (blockIdx.x * 256 + threadIdx.x) * 8;
#pragma unroll
  for (int half = 0; half < 2; ++half) {
    float4 a = *reinterpret_cast<const float4*>(in + i + half * 4);
    ushort4 h4;
    h4.x = f2bf(a.x); h4.y = f2bf(a.y); h4.z = f2bf(a.z); h4.w = f2bf(a.w);
    *reinterpret_cast<ushort4*>(out + i + half * 4) = h4;
  }
}

// ---------------- cast weights fp32 -> bf16 ----------------
__global__ __launch_bounds__(256) void cast_w_kernel(const float* __restrict__ in,
                                                     unsigned short* __restrict__ out) {
  size_t i = ((size_t)blockIdx.x * 256 + threadIdx.x) * 8;
#pragma unroll
  for (int half = 0; half < 2; ++half) {
    float4 a = *reinterpret_cast<const float4*>(in + i + half * 4);
    ushort4 h4;
    h4.x = f2bf(a.x); h4.y = f2bf(a.y); h4.z = f2bf(a.z); h4.w = f2bf(a.w);
    *reinterpret_cast<ushort4*>(out + i + half * 4) = h4;
  }
}

// ---------------- router: sigmoid top-2 + token lists + weights ----------------
__global__ __launch_bounds__(256) void router_kernel(
    const float* __restrict__ x, const float* __restrict__ rw,
    const float* __restrict__ bias, int* __restrict__ cnt,
    int* __restrict__ list, float* __restrict__ wlist) {
  __shared__ float rws[NEXP * DIM_];
  for (int i = threadIdx.x; i < NEXP * DIM_ / 4; i += 256)
    reinterpret_cast<float4*>(rws)[i] = reinterpret_cast<const float4*>(rw)[i];
  __syncthreads();
  int wave = threadIdx.x >> 6, lane = threadIdx.x & 63;
  int t = blockIdx.x * 4 + wave;
  const float* xr = x + (size_t)t * DIM_;
  float p[NEXP];
#pragma unroll
  for (int e = 0; e < NEXP; ++e) p[e] = 0.f;
  for (int i = 0; i < DIM_ / 64; ++i) {
    float xv = xr[i * 64 + lane];
#pragma unroll
    for (int e = 0; e < NEXP; ++e) p[e] += xv * rws[e * DIM_ + i * 64 + lane];
  }
#pragma unroll
  for (int e = 0; e < NEXP; ++e) {
#pragma unroll
    for (int s = 32; s > 0; s >>= 1) p[e] += __shfl_xor(p[e], s);
  }
  if (lane == 0) {
    float sc[NEXP];
#pragma unroll
    for (int e = 0; e < NEXP; ++e) sc[e] = 1.f / (1.f + __expf(-(p[e] + bias[e])));
    int e0 = 0; float s0 = sc[0];
#pragma unroll
    for (int e = 1; e < NEXP; ++e) if (sc[e] > s0) { s0 = sc[e]; e0 = e; }
    int e1 = -1; float s1 = -1.f;
#pragma unroll
    for (int e = 0; e < NEXP; ++e) if (e != e0 && sc[e] > s1) { s1 = sc[e]; e1 = e; }
    float inv = 1.f / (s0 + s1 + 1e-6f);
    int p0 = atomicAdd(&cnt[e0], 1);
    list[e0 * T_TOK + p0] = t; wlist[e0 * T_TOK + p0] = s0 * inv;
    int p1 = atomicAdd(&cnt[e1], 1);
    list[e1 * T_TOK + p1] = t; wlist[e1 * T_TOK + p1] = s1 * inv;
  }
}

// ---------------- tiny exclusive scan over 8 counts ----------------
__global__ void scan_kernel(const int* __restrict__ cnt, int* __restrict__ off) {
  if (threadIdx.x == 0) {
    int a = 0;
#pragma unroll
    for (int e = 0; e < NEXP; ++e) { off[e] = a; a += cnt[e]; }
  }
}

// ==================================================================
// gate+up GEMM + silu -> h (bf16). Tile 128(M) x 256(N), BK=64.
// 1024 threads = 16 waves (2m x 8n). A = gathered xbf rows (gld_lds,
// pre-swizzled src); B = bf16 weights (gld_lds, pre-swizzled src).
// Grid: x = bn (fast), y = mb, z = expert.
// ==================================================================
template <bool EXPERT>
__global__ __launch_bounds__(1024) void gateup_k(
    const unsigned short* __restrict__ xbf,
    const unsigned short* __restrict__ gwb_, const unsigned short* __restrict__ uwb_,
    const int* __restrict__ cnt, const int* __restrict__ off,
    const int* __restrict__ list, unsigned short* __restrict__ hout) {
  const int e = EXPERT ? blockIdx.z : 0;
  const int cnt_e = EXPERT ? cnt[e] : T_TOK;
  const int bn = blockIdx.x, mb = blockIdx.y;
  if (mb * 128 >= cnt_e) return;
  const int rowoff = EXPERT ? off[e] : 0;

  __shared__ unsigned short As[128 * 64];   // 16 KB
  __shared__ unsigned short Bg[256 * 64];   // 32 KB
  __shared__ unsigned short Bu[256 * 64];   // 32 KB

  const int tid = threadIdx.x;
  const size_t eoff = EXPERT ? (size_t)e * HID_ * DIM_ : 0;
  const unsigned short* gwb = gwb_ + eoff;
  const unsigned short* uwb = uwb_ + eoff;

  // A: 1024 chunks, 1 per thread. chunk c -> row c>>3, global unit (c&7)^(r&7)
  size_t arow;
  {
    int c = tid;
    int r = c >> 3;
    int u = (c & 7) ^ (r & 7);
    int rl = mb * 128 + r;
    int gr;
    if (EXPERT) { int cl = rl < cnt_e ? rl : cnt_e - 1; gr = list[e * T_TOK + cl]; }
    else gr = rl;
    arow = (size_t)gr * DIM_ + (size_t)(u * 8);
  }
  // B: 2048 chunks each, 2 per thread.
  size_t brow[2];
#pragma unroll
  for (int j = 0; j < 2; ++j) {
    int c = tid + j * 1024;
    int r = c >> 3;
    int u = (c & 7) ^ (r & 7);
    brow[j] = (size_t)(bn * 256 + r) * DIM_ + (size_t)(u * 8);
  }

  const f32x4 vzero = {0.f, 0.f, 0.f, 0.f};
  f32x4 accg[4][2], accu[4][2];
#pragma unroll
  for (int m = 0; m < 4; ++m)
#pragma unroll
    for (int n = 0; n < 2; ++n) { accg[m][n] = vzero; accu[m][n] = vzero; }

  const int wid = tid >> 6, lane = tid & 63;
  const int wm = wid >> 3, wn = wid & 7;      // 2 x 8 wave grid
  const int fr = lane & 15, fk = (lane >> 4) * 8;

  for (int k0 = 0; k0 < DIM_; k0 += 64) {
    __syncthreads();
    gld_lds16(xbf + arow + k0, &As[tid * 8]);
#pragma unroll
    for (int j = 0; j < 2; ++j) {
      int c = tid + j * 1024;
      gld_lds16(gwb + brow[j] + k0, &Bg[c * 8]);
      gld_lds16(uwb + brow[j] + k0, &Bu[c * 8]);
    }
    __syncthreads();
#pragma unroll
    for (int kk = 0; kk < 64; kk += 32) {
      bf16x8 a[4], bg[2], bu[2];
#pragma unroll
      for (int m = 0; m < 4; ++m) {
        int ar = wm * 64 + m * 16 + fr;
        a[m] = *reinterpret_cast<const bf16x8*>(&As[lds_idx(ar, kk + fk)]);
      }
#pragma unroll
      for (int n = 0; n < 2; ++n) {
        int br = wn * 32 + n * 16 + fr;
        bg[n] = *reinterpret_cast<const bf16x8*>(&Bg[lds_idx(br, kk + fk)]);
        bu[n] = *reinterpret_cast<const bf16x8*>(&Bu[lds_idx(br, kk + fk)]);
      }
#pragma unroll
      for (int m = 0; m < 4; ++m)
#pragma unroll
        for (int n = 0; n < 2; ++n) {
          accg[m][n] = __builtin_amdgcn_mfma_f32_16x16x32_bf16(a[m], bg[n], accg[m][n], 0, 0, 0);
          accu[m][n] = __builtin_amdgcn_mfma_f32_16x16x32_bf16(a[m], bu[n], accu[m][n], 0, 0, 0);
        }
    }
  }

  const int rb = mb * 128 + wm * 64 + (lane >> 4) * 4;
  const int cb = bn * 256 + wn * 32 + fr;
#pragma unroll
  for (int m = 0; m < 4; ++m) {
#pragma unroll
    for (int r = 0; r < 4; ++r) {
      int rl = rb + m * 16 + r;
      if (EXPERT && rl >= cnt_e) continue;
      size_t rowbase = (size_t)(rowoff + rl) * HID_ + cb;
#pragma unroll
      for (int n = 0; n < 2; ++n) {
        float g = accg[m][n][r], u = accu[m][n][r];
        float hv = (g / (1.f + __expf(-g))) * u;
        hout[rowbase + n * 16] = f2bf(hv);
      }
    }
  }
}

// ==================================================================
// down GEMM. Tile 128(M) x 256(N), BK=64, 512 threads = 8 waves (2m x 4n).
// EXPERT: out[token] += w_e * y  (atomicAdd); shared: out[token] = y (store).
// ==================================================================
template <bool EXPERT>
__global__ __launch_bounds__(512) void down_k(
    const unsigned short* __restrict__ h, const unsigned short* __restrict__ dwb_,
    const int* __restrict__ cnt, const int* __restrict__ off,
    const int* __restrict__ list, const float* __restrict__ wlist,
    float* __restrict__ out) {
  const int e = EXPERT ? blockIdx.z : 0;
  const int cnt_e = EXPERT ? cnt[e] : T_TOK;
  const int bn = blockIdx.x, mb = blockIdx.y;
  if (mb * 128 >= cnt_e) return;
  const int rowoff = EXPERT ? off[e] : 0;

  __shared__ unsigned short As[128 * 64];   // 16 KB
  __shared__ unsigned short Bs[256 * 64];   // 32 KB

  const int tid = threadIdx.x;
  const unsigned short* dwb = dwb_ + (EXPERT ? (size_t)e * DIM_ * HID_ : 0);

  size_t arow[2];
#pragma unroll
  for (int j = 0; j < 2; ++j) {
    int c = tid + j * 512;
    int r = c >> 3;
    int u = (c & 7) ^ (r & 7);
    int rl = mb * 128 + r;
    int cl = (EXPERT && rl >= cnt_e) ? cnt_e - 1 : rl;
    arow[j] = (size_t)(rowoff + cl) * HID_ + (size_t)(u * 8);
  }
  size_t brow[4];
#pragma unroll
  for (int j = 0; j < 4; ++j) {
    int c = tid + j * 512;
    int r = c >> 3;
    int u = (c & 7) ^ (r & 7);
    brow[j] = (size_t)(bn * 256 + r) * HID_ + (size_t)(u * 8);
  }

  const f32x4 vzero = {0.f, 0.f, 0.f, 0.f};
  f32x4 acc[4][4];
#pragma unroll
  for (int m = 0; m < 4; ++m)
#pragma unroll
    for (int n = 0; n < 4; ++n) acc[m][n] = vzero;

  const int wid = tid >> 6, lane = tid & 63;
  const int wm = wid >> 2, wn = wid & 3;      // 2 x 4 wave grid
  const int fr = lane & 15, fk = (lane >> 4) * 8;

  for (int k0 = 0; k0 < HID_; k0 += 64) {
    __syncthreads();
#pragma unroll
    for (int j = 0; j < 2; ++j) {
      int c = tid + j * 512;
      gld_lds16(h + arow[j] + k0, &As[c * 8]);
    }
#pragma unroll
    for (int j = 0; j < 4; ++j) {
      int c = tid + j * 512;
      gld_lds16(dwb + brow[j] + k0, &Bs[c * 8]);
    }
    __syncthreads();
#pragma unroll
    for (int kk = 0; kk < 64; kk += 32) {
      bf16x8 a[4], b[4];
#pragma unroll
      for (int m = 0; m < 4; ++m) {
        int ar = wm * 64 + m * 16 + fr;
        a[m] = *reinterpret_cast<const bf16x8*>(&As[lds_idx(ar, kk + fk)]);
      }
#pragma unroll
      for (int n = 0; n < 4; ++n) {
        int br = wn * 64 + n * 16 + fr;
        b[n] = *reinterpret_cast<const bf16x8*>(&Bs[lds_idx(br, kk + fk)]);
      }
#pragma unroll
      for (int m = 0; m < 4; ++m)
#pragma unroll
        for (int n = 0; n < 4; ++n)
          acc[m][n] = __builtin_amdgcn_mfma_f32_16x16x32_bf16(a[m], b[n], acc[m][n], 0, 0, 0);
    }
  }

  const int rb = mb * 128 + wm * 64 + (lane >> 4) * 4;
  const int cb = bn * 256 + wn * 64 + fr;
#pragma unroll
  for (int m = 0; m < 4; ++m) {
#pragma unroll
    for (int r = 0; r < 4; ++r) {
      int rl = rb + m * 16 + r;
      if (EXPERT && rl >= cnt_e) continue;
      if (EXPERT) {
        int tok = list[e * T_TOK + rl];
        float w = wlist[e * T_TOK + rl];
        float* orow = out + (size_t)tok * DIM_ + cb;
#pragma unroll
        for (int n = 0; n < 4; ++n)
          atomicAdd(orow + n * 16, w * acc[m][n][r]);
      } else {
        float* orow = out + (size_t)rl * DIM_ + cb;
#pragma unroll
        for (int n = 0; n < 4; ++n)
          orow[n * 16] = acc[m][n][r];
      }
    }
  }
}

extern "C" void kernel_launch(void* const* d_in, const int* in_sizes, int n_in,
                              void* d_out, int out_size, void* d_ws, size_t ws_size,
                              hipStream_t stream) {
  const float* x    = (const float*)d_in[0];
  const float* rw   = (const float*)d_in[1];
  const float* bias = (const float*)d_in[2];
  const float* gw   = (const float*)d_in[3];
  const float* uw   = (const float*)d_in[4];
  const float* dwn  = (const float*)d_in[5];
  const float* sgw  = (const float*)d_in[6];
  const float* suw  = (const float*)d_in[7];
  const float* sdw  = (const float*)d_in[8];
  float* out = (float*)d_out;

  char* ws = (char*)d_ws;
  size_t o = 0;
  auto alloc = [&](size_t b) { size_t r = o; o = (o + b + 255) & ~(size_t)255; return r; };
  unsigned short* xbf = (unsigned short*)(ws + alloc((size_t)T_TOK * DIM_ * 2));
  unsigned short* h   = (unsigned short*)(ws + alloc(((size_t)2 * T_TOK + 128) * HID_ * 2));
  int*   cnt   = (int*)(ws + alloc(NEXP * 4));
  int*   off   = (int*)(ws + alloc(NEXP * 4));
  int*   list  = (int*)(ws + alloc((size_t)NEXP * T_TOK * 4));
  float* wlist = (float*)(ws + alloc((size_t)NEXP * T_TOK * 4));
  const size_t WE = (size_t)HID_ * DIM_;
  unsigned short* gwb  = (unsigned short*)(ws + alloc(NEXP * WE * 2));
  unsigned short* uwb  = (unsigned short*)(ws + alloc(NEXP * WE * 2));
  unsigned short* dwb  = (unsigned short*)(ws + alloc(NEXP * WE * 2));
  unsigned short* sgwb = (unsigned short*)(ws + alloc(WE * 2));
  unsigned short* suwb = (unsigned short*)(ws + alloc(WE * 2));
  unsigned short* sdwb = (unsigned short*)(ws + alloc(WE * 2));
  if (o > ws_size) {  // precast must fit (proven >= ~266 MB); fail visibly otherwise
    hipMemsetAsync(d_out, 0, (size_t)out_size * 4, stream);
    return;
  }

  hipMemsetAsync(cnt, 0, NEXP * 4, stream);
  cast_x_kernel<<<T_TOK * DIM_ / 8 / 256, 256, 0, stream>>>(x, xbf);
  router_kernel<<<T_TOK / 4, 256, 0, stream>>>(x, rw, bias, cnt, list, wlist);
  scan_kernel<<<1, 64, 0, stream>>>(cnt, off);

  const int WB = (int)(NEXP * WE / 2048);
  const int WS = (int)(WE / 2048);
  cast_w_kernel<<<WB, 256, 0, stream>>>(gw,  gwb);
  cast_w_kernel<<<WB, 256, 0, stream>>>(uw,  uwb);
  cast_w_kernel<<<WB, 256, 0, stream>>>(dwn, dwb);
  cast_w_kernel<<<WS, 256, 0, stream>>>(sgw, sgwb);
  cast_w_kernel<<<WS, 256, 0, stream>>>(suw, suwb);
  cast_w_kernel<<<WS, 256, 0, stream>>>(sdw, sdwb);

  // shared expert: h rows [0,T), down does plain stores (initializes out)
  gateup_k<false><<<dim3(HID_ / 256, T_TOK / 128, 1), 1024, 0, stream>>>(
      xbf, sgwb, suwb, cnt, off, list, h);
  down_k<false><<<dim3(DIM_ / 256, T_TOK / 128, 1), 512, 0, stream>>>(
      h, sdwb, cnt, off, list, wlist, out);
  // routed experts: h rows [0,2T) packed, down adds w_e * y atomically
  gateup_k<true><<<dim3(HID_ / 256, T_TOK / 128, NEXP), 1024, 0, stream>>>(
      xbf, gwb, uwb, cnt, off, list, h);
  down_k<true><<<dim3(DIM_ / 256, T_TOK / 128, NEXP), 512, 0, stream>>>(
      h, dwb, cnt, off, list, wlist, out);
}